// Round 3
// baseline (355.532 us; speedup 1.0000x reference)
//
#include <hip/hip_runtime.h>

#define BLOCK 256
#define RPT   4                       // rows per thread
#define RPB   (BLOCK * RPT)           // 1024 rows per block

// One row of the model: probs -> (copy_mask, child2copy, alpha_mask, alpha).
// p[3], c[3], e[9] in registers; mu/sg gathered from LDS (tiny table).
__device__ __forceinline__ void row_compute(
    const float* p, const float* c, const float* e,
    float bb, int rq,
    const float* smu, const float* ssg,
    float* o1, float* o3, float& m0v, float& m2v)
{
    const float* mu = &smu[9 * rq];
    const float* sg = &ssg[9 * rq];

    // logits = (mu + sigma*eps) @ child
    float l[3];
    #pragma unroll
    for (int i = 0; i < 3; ++i) {
        float acc = 0.0f;
        #pragma unroll
        for (int j = 0; j < 3; ++j) {
            float m = fmaf(sg[3 * i + j], e[3 * i + j], mu[3 * i + j]);
            acc = fmaf(m, c[j], acc);
        }
        l[i] = acc;
    }
    // softmax (3-wide)
    float mx = fmaxf(l[0], fmaxf(l[1], l[2]));
    float e0 = __expf(l[0] - mx), e1 = __expf(l[1] - mx), e2 = __expf(l[2] - mx);
    float einv = 1.0f / (e0 + e1 + e2);
    float cp0 = e0 * einv, cp1 = e1 * einv, cp2 = e2 * einv;

    float csum = c[0] + c[1] + c[2];
    float psum = p[0] + p[1] + p[2];
    bool cmask = (csum != 0.0f);
    bool copy  = cmask && (psum == 0.0f);
    bool amask = cmask && (psum != 0.0f);

    // _scale(prnt, cp)
    float z0 = fmaxf(0.01f, p[0] + cp0);
    float z1 = fmaxf(0.01f, p[1] + cp1);
    float z2 = fmaxf(0.01f, p[2] + cp2);
    float zinv = 1.0f / (z0 + z1 + z2);
    z0 *= zinv; z1 *= zinv; z2 *= zinv;
    float ent = -(z0 * __logf(z0) + z1 * __logf(z1) + z2 * __logf(z2));
    float cosv = p[0] * cp0 + p[1] * cp1 + p[2] * cp2;
    float np2 = p[0] * p[0] + p[1] * p[1] + p[2] * p[2];
    float nc2 = cp0 * cp0 + cp1 * cp1 + cp2 * cp2;
    float npn = (np2 == 0.0f) ? 0.0f : sqrtf(np2);
    float ncn = (nc2 == 0.0f) ? 0.0f : sqrtf(nc2);
    float nrm = npn * ncn;
    nrm = (nrm == 0.0f) ? 1.0f : nrm;
    cosv = fmaxf(0.01f, cosv / nrm);
    float s = 42.0f * cosv / ent;

    float ob = 1.0f - bb;
    float a0 = fmaf(ob, p[0], bb * cp0) * s;
    float a1 = fmaf(ob, p[1], bb * cp1) * s;
    float a2 = fmaf(ob, p[2], bb * cp2) * s;

    m0v = copy  ? 1.0f : 0.0f;
    m2v = amask ? 1.0f : 0.0f;
    o1[0] = copy ? cp0 : 0.0f;
    o1[1] = copy ? cp1 : 0.0f;
    o1[2] = copy ? cp2 : 0.0f;
    o3[0] = amask ? a0 : 0.0f;
    o3[1] = amask ? a1 : 0.0f;
    o3[2] = amask ? a2 : 0.0f;
}

// No input staging, no vmcnt(0) drains, one startup barrier only (mu table).
// Each thread owns 4 rows: all loads/stores are float4, waves free-run.
__global__ __launch_bounds__(BLOCK, 2) void alpha_kernel(
    const float* __restrict__ prnt,
    const float* __restrict__ child,
    const float* __restrict__ rel_mu,
    const float* __restrict__ rel_sigma,
    const float* __restrict__ eps,
    const float* __restrict__ beta,
    const int*  __restrict__ rels,
    float* __restrict__ out0,   // copy_mask        (N floats)
    float* __restrict__ out1,   // child_probs2copy (3N floats)
    float* __restrict__ out2,   // alpha_mask       (N floats)
    float* __restrict__ out3,   // alpha            (3N floats)
    int n_rows, int nmu)
{
    __shared__ float smu[192];
    __shared__ float ssg[192];

    const int tid = threadIdx.x;
    if (tid < nmu) { smu[tid] = rel_mu[tid]; ssg[tid] = rel_sigma[tid]; }
    __syncthreads();

    const long T  = (long)blockIdx.x * BLOCK + tid;   // thread id
    const long r0 = T * RPT;                          // first row of this thread
    if (r0 >= n_rows) return;

    if (r0 + RPT <= n_rows) {
        // ---- full vector path: 17 float4/int4 loads, 8 float4 stores ----
        const float4* p4 = (const float4*)prnt;
        const float4* c4 = (const float4*)child;
        const float4* e4 = (const float4*)eps;
        const float4* b4 = (const float4*)beta;
        const int4*   r4 = (const int4*)rels;

        float4 P[3], C[3], E[9];
        #pragma unroll
        for (int k = 0; k < 3; ++k) P[k] = p4[3 * T + k];
        #pragma unroll
        for (int k = 0; k < 3; ++k) C[k] = c4[3 * T + k];
        #pragma unroll
        for (int k = 0; k < 9; ++k) E[k] = e4[9 * T + k];
        float4 bt = b4[T];
        int4   rl = r4[T];

        const float* Pf = (const float*)P;
        const float* Cf = (const float*)C;
        const float* Ef = (const float*)E;
        float bq[RPT] = {bt.x, bt.y, bt.z, bt.w};
        int   rq[RPT] = {rl.x, rl.y, rl.z, rl.w};

        float o1[12], o3[12], m0[RPT], m2[RPT];
        #pragma unroll
        for (int r = 0; r < RPT; ++r) {
            row_compute(Pf + 3 * r, Cf + 3 * r, Ef + 9 * r,
                        bq[r], rq[r], smu, ssg,
                        o1 + 3 * r, o3 + 3 * r, m0[r], m2[r]);
        }

        ((float4*)out0)[T] = make_float4(m0[0], m0[1], m0[2], m0[3]);
        ((float4*)out2)[T] = make_float4(m2[0], m2[1], m2[2], m2[3]);
        float4* o1g = (float4*)out1;
        float4* o3g = (float4*)out3;
        const float4* o1l = (const float4*)o1;
        const float4* o3l = (const float4*)o3;
        #pragma unroll
        for (int k = 0; k < 3; ++k) o1g[3 * T + k] = o1l[k];
        #pragma unroll
        for (int k = 0; k < 3; ++k) o3g[3 * T + k] = o3l[k];
    } else {
        // ---- ragged tail: scalar per-row path (unused when N % 4 == 0) ----
        for (long r = r0; r < n_rows; ++r) {
            float p[3], c[3], e[9];
            #pragma unroll
            for (int k = 0; k < 3; ++k) p[k] = prnt[3 * r + k];
            #pragma unroll
            for (int k = 0; k < 3; ++k) c[k] = child[3 * r + k];
            #pragma unroll
            for (int k = 0; k < 9; ++k) e[k] = eps[9 * r + k];
            float o1s[3], o3s[3], m0s, m2s;
            row_compute(p, c, e, beta[r], rels[r], smu, ssg, o1s, o3s, m0s, m2s);
            out0[r] = m0s;
            out2[r] = m2s;
            #pragma unroll
            for (int k = 0; k < 3; ++k) out1[3 * r + k] = o1s[k];
            #pragma unroll
            for (int k = 0; k < 3; ++k) out3[3 * r + k] = o3s[k];
        }
    }
}

extern "C" void kernel_launch(void* const* d_in, const int* in_sizes, int n_in,
                              void* d_out, int out_size, void* d_ws, size_t ws_size,
                              hipStream_t stream)
{
    const float* prnt      = (const float*)d_in[0];
    const float* child     = (const float*)d_in[1];
    const float* rel_mu    = (const float*)d_in[2];
    const float* rel_sigma = (const float*)d_in[3];
    const float* eps       = (const float*)d_in[4];
    const float* beta      = (const float*)d_in[5];
    const int*   rels      = (const int*)d_in[6];

    const int N   = in_sizes[5];   // 4,000,000
    const int nmu = in_sizes[2];   // 180

    float* out  = (float*)d_out;
    float* out0 = out;                      // copy_mask        [N]
    float* out1 = out + (size_t)N;          // child_probs2copy [N,3]
    float* out2 = out + (size_t)4 * N;      // alpha_mask       [N]
    float* out3 = out + (size_t)5 * N;      // alpha            [N,3]

    int blocks = (N + RPB - 1) / RPB;
    alpha_kernel<<<blocks, BLOCK, 0, stream>>>(
        prnt, child, rel_mu, rel_sigma, eps, beta, rels,
        out0, out1, out2, out3, N, nmu);
}

// Round 4
// 341.216 us; speedup vs baseline: 1.0420x; 1.0420x over previous
//
#include <hip/hip_runtime.h>

#define BLOCK 256
#define TILE  256                 // rows per tile, 1 row per thread
#define GBLK  1024                // grid-stride width (4 per CU queued, 3 resident)

typedef const __attribute__((address_space(1))) void* gas1_t;
typedef __attribute__((address_space(3)))       void* las3_t;

// Async direct-to-LDS 16B load: lane L loads g[L] into lds_base + L*16.
__device__ __forceinline__ void ld_lds16(const float4* g, float4* l) {
    __builtin_amdgcn_global_load_lds((gas1_t)(const void*)g, (las3_t)(void*)l, 16, 0, 0);
}

// alpha barrier: LDS writes visible, vmem queue (prefetch) untouched.
__device__ __forceinline__ void bar_lgkm0() {
    asm volatile("s_waitcnt lgkmcnt(0)" ::: "memory");
    __builtin_amdgcn_sched_barrier(0);
    __builtin_amdgcn_s_barrier();
    __builtin_amdgcn_sched_barrier(0);
}
// beta barrier: allow the 5 newest vmem ops (this iter's stores) to stay in
// flight; everything older (the 17 prefetch global_load_lds, issued before the
// stores) is forced complete -> next buffer is published. Never drains to 0.
__device__ __forceinline__ void bar_vm5_lgkm0() {
    asm volatile("s_waitcnt vmcnt(5) lgkmcnt(0)" ::: "memory");
    __builtin_amdgcn_sched_barrier(0);
    __builtin_amdgcn_s_barrier();
    __builtin_amdgcn_sched_barrier(0);
}

__device__ __forceinline__ void row_compute(
    const float* p, const float* c, const float* e,
    float bb, int rq,
    const float* smu, const float* ssg,
    float* o1, float* o3, float& m0v, float& m2v)
{
    const float* mu = &smu[9 * rq];
    const float* sg = &ssg[9 * rq];

    float l[3];
    #pragma unroll
    for (int i = 0; i < 3; ++i) {
        float acc = 0.0f;
        #pragma unroll
        for (int j = 0; j < 3; ++j) {
            float m = fmaf(sg[3 * i + j], e[3 * i + j], mu[3 * i + j]);
            acc = fmaf(m, c[j], acc);
        }
        l[i] = acc;
    }
    float mx = fmaxf(l[0], fmaxf(l[1], l[2]));
    float e0 = __expf(l[0] - mx), e1 = __expf(l[1] - mx), e2 = __expf(l[2] - mx);
    float einv = 1.0f / (e0 + e1 + e2);
    float cp0 = e0 * einv, cp1 = e1 * einv, cp2 = e2 * einv;

    float csum = c[0] + c[1] + c[2];
    float psum = p[0] + p[1] + p[2];
    bool cmask = (csum != 0.0f);
    bool copy  = cmask && (psum == 0.0f);
    bool amask = cmask && (psum != 0.0f);

    float z0 = fmaxf(0.01f, p[0] + cp0);
    float z1 = fmaxf(0.01f, p[1] + cp1);
    float z2 = fmaxf(0.01f, p[2] + cp2);
    float zinv = 1.0f / (z0 + z1 + z2);
    z0 *= zinv; z1 *= zinv; z2 *= zinv;
    float ent = -(z0 * __logf(z0) + z1 * __logf(z1) + z2 * __logf(z2));
    float cosv = p[0] * cp0 + p[1] * cp1 + p[2] * cp2;
    float np2 = p[0] * p[0] + p[1] * p[1] + p[2] * p[2];
    float nc2 = cp0 * cp0 + cp1 * cp1 + cp2 * cp2;
    float npn = (np2 == 0.0f) ? 0.0f : sqrtf(np2);
    float ncn = (nc2 == 0.0f) ? 0.0f : sqrtf(nc2);
    float nrm = npn * ncn;
    nrm = (nrm == 0.0f) ? 1.0f : nrm;
    cosv = fmaxf(0.01f, cosv / nrm);
    float s = 42.0f * cosv / ent;

    float ob = 1.0f - bb;
    float a0 = fmaf(ob, p[0], bb * cp0) * s;
    float a1 = fmaf(ob, p[1], bb * cp1) * s;
    float a2 = fmaf(ob, p[2], bb * cp2) * s;

    m0v = copy  ? 1.0f : 0.0f;
    m2v = amask ? 1.0f : 0.0f;
    o1[0] = copy ? cp0 : 0.0f;
    o1[1] = copy ? cp1 : 0.0f;
    o1[2] = copy ? cp2 : 0.0f;
    o3[0] = amask ? a0 : 0.0f;
    o3[1] = amask ? a1 : 0.0f;
    o3[2] = amask ? a2 : 0.0f;
}

// Double-buffered grid-stride pipeline: while tile t is computed from buf[cur],
// tile t+G streams into buf[cur^1] via global_load_lds (0 VGPR cost).
// 42.5 KB LDS -> 3 blocks/CU. Two raw barriers/iter, counted vmcnt, no drains.
__global__ __launch_bounds__(BLOCK, 3) void alpha_kernel(
    const float4* __restrict__ prnt4,
    const float4* __restrict__ child4,
    const float*  __restrict__ rel_mu,
    const float*  __restrict__ rel_sigma,
    const float4* __restrict__ eps4,
    const float4* __restrict__ beta4,
    const float4* __restrict__ rels4,     // int data, staged as bytes
    float* __restrict__ out0,             // copy_mask        (N)
    float* __restrict__ out1,             // child_probs2copy (3N)
    float* __restrict__ out2,             // alpha_mask       (N)
    float* __restrict__ out3,             // alpha            (3N)
    int n_rows, int nmu)
{
    __shared__ float4 s_p[2][192];
    __shared__ float4 s_c[2][192];
    __shared__ float4 s_e[2][576];
    __shared__ float4 s_b[2][64];
    __shared__ float4 s_r[2][64];
    __shared__ float  s_ob[1536];        // 6 KB output bounce (o1 | o3)
    __shared__ float  smu[192], ssg[192];

    const int tid  = threadIdx.x;
    const int lane = tid & 63;
    const int wv   = tid >> 6;
    const int nt   = (n_rows + TILE - 1) / TILE;
    const int G    = (int)gridDim.x;

    if (tid < nmu) { smu[tid] = rel_mu[tid]; ssg[tid] = rel_sigma[tid]; }

    // ---- stage tile t into buffer bb (async when full, guarded when ragged)
    auto stage = [&](int t, int bb) {
        const int rows = min(TILE, n_rows - t * TILE);
        if (rows == TILE) {
            const float4* gp = prnt4  + (size_t)t * 192;
            const float4* gc = child4 + (size_t)t * 192;
            const float4* ge = eps4   + (size_t)t * 576;
            const float4* gb = beta4  + (size_t)t * 64;
            const float4* gr = rels4  + (size_t)t * 64;
            for (int ch = wv; ch < 17; ch += 4) {     // waves get 5/4/4/4 chunks
                if      (ch < 3)  ld_lds16(gp + ch * 64 + lane,       &s_p[bb][ch * 64]);
                else if (ch < 6)  ld_lds16(gc + (ch - 3) * 64 + lane, &s_c[bb][(ch - 3) * 64]);
                else if (ch < 15) ld_lds16(ge + (ch - 6) * 64 + lane, &s_e[bb][(ch - 6) * 64]);
                else if (ch == 15) ld_lds16(gb + lane, &s_b[bb][0]);
                else               ld_lds16(gr + lane, &s_r[bb][0]);
            }
        } else {
            // ragged tile (never hit at N=4M): guarded scalar staging
            const float* gpf = (const float*)prnt4;
            const float* gcf = (const float*)child4;
            const float* gef = (const float*)eps4;
            const float* gbf = (const float*)beta4;
            const int*   gri = (const int*)rels4;
            for (int i = tid; i < rows * 3; i += BLOCK) {
                ((float*)&s_p[bb][0])[i] = gpf[(size_t)t * 768 + i];
                ((float*)&s_c[bb][0])[i] = gcf[(size_t)t * 768 + i];
            }
            for (int i = tid; i < rows * 9; i += BLOCK)
                ((float*)&s_e[bb][0])[i] = gef[(size_t)t * 2304 + i];
            for (int i = tid; i < rows; i += BLOCK) {
                ((float*)&s_b[bb][0])[i] = gbf[(size_t)t * 256 + i];
                ((int*)&s_r[bb][0])[i]   = gri[(size_t)t * 256 + i];
            }
        }
    };

    int t = blockIdx.x;
    int cur = 0;
    if (t < nt) stage(t, 0);
    __syncthreads();                      // prologue full drain (once)

    while (t < nt) {
        const int nxt = t + G;
        if (nxt < nt) stage(nxt, cur ^ 1);          // prefetch next tile

        const int rows_here = min(TILE, n_rows - t * TILE);
        if (rows_here == TILE) {
            // ---- compute tile t from buf[cur] (1 row per thread)
            const float* pf = (const float*)&s_p[cur][0];
            const float* cf = (const float*)&s_c[cur][0];
            const float* ef = (const float*)&s_e[cur][0];
            float p[3], c[3], e[9];
            #pragma unroll
            for (int k = 0; k < 3; ++k) p[k] = pf[3 * tid + k];
            #pragma unroll
            for (int k = 0; k < 3; ++k) c[k] = cf[3 * tid + k];
            #pragma unroll
            for (int k = 0; k < 9; ++k) e[k] = ef[9 * tid + k];
            const float bb = ((const float*)&s_b[cur][0])[tid];
            const int   rq = ((const int*)&s_r[cur][0])[tid];

            float o1[3], o3[3], m0, m2;
            row_compute(p, c, e, bb, rq, smu, ssg, o1, o3, m0, m2);

            // stores 1+2: masks, contiguous dwords
            out0[(size_t)t * 256 + tid] = m0;
            out2[(size_t)t * 256 + tid] = m2;

            // bounce o1/o3 -> LDS (stride-3 dwords: conflict-free)
            #pragma unroll
            for (int k = 0; k < 3; ++k) s_ob[3 * tid + k]       = o1[k];
            #pragma unroll
            for (int k = 0; k < 3; ++k) s_ob[768 + 3 * tid + k] = o3[k];

            bar_lgkm0();                              // alpha: bounce visible

            // stores 3..5: coalesced float2, 768 f2 total across 256 threads
            const float2* ob2 = (const float2*)s_ob;
            float2* o1g = (float2*)out1 + (size_t)t * 384;
            float2* o3g = (float2*)out3 + (size_t)t * 384;
            #pragma unroll
            for (int j = 0; j < 3; ++j) {
                const int i = tid + 256 * j;
                float2 v = ob2[i];
                float2* dst = (i < 384) ? (o1g + i) : (o3g + (i - 384));
                *dst = v;
            }

            bar_vm5_lgkm0();     // beta: publish buf[cur^1]; 5 stores may fly
        } else {
            // ragged tile: direct guarded path, full drain (at most once ever)
            const bool act = tid < rows_here;
            if (act) {
                const size_t r = (size_t)t * 256 + tid;
                const float* gpf = (const float*)prnt4;
                const float* gcf = (const float*)child4;
                const float* gef = (const float*)eps4;
                float p[3], c[3], e[9];
                #pragma unroll
                for (int k = 0; k < 3; ++k) p[k] = gpf[3 * r + k];
                #pragma unroll
                for (int k = 0; k < 3; ++k) c[k] = gcf[3 * r + k];
                #pragma unroll
                for (int k = 0; k < 9; ++k) e[k] = gef[9 * r + k];
                const float bb = ((const float*)beta4)[r];
                const int   rq = ((const int*)rels4)[r];
                float o1[3], o3[3], m0, m2;
                row_compute(p, c, e, bb, rq, smu, ssg, o1, o3, m0, m2);
                out0[r] = m0;
                out2[r] = m2;
                #pragma unroll
                for (int k = 0; k < 3; ++k) out1[3 * r + k] = o1[k];
                #pragma unroll
                for (int k = 0; k < 3; ++k) out3[3 * r + k] = o3[k];
            }
            __syncthreads();
        }

        cur ^= 1;
        t = nxt;
    }
}

extern "C" void kernel_launch(void* const* d_in, const int* in_sizes, int n_in,
                              void* d_out, int out_size, void* d_ws, size_t ws_size,
                              hipStream_t stream)
{
    const float* prnt      = (const float*)d_in[0];
    const float* child     = (const float*)d_in[1];
    const float* rel_mu    = (const float*)d_in[2];
    const float* rel_sigma = (const float*)d_in[3];
    const float* eps       = (const float*)d_in[4];
    const float* beta      = (const float*)d_in[5];
    const int*   rels      = (const int*)d_in[6];

    const int N   = in_sizes[5];   // 4,000,000
    const int nmu = in_sizes[2];   // 180

    float* out  = (float*)d_out;
    float* out0 = out;                      // copy_mask        [N]
    float* out1 = out + (size_t)N;          // child_probs2copy [N,3]
    float* out2 = out + (size_t)4 * N;      // alpha_mask       [N]
    float* out3 = out + (size_t)5 * N;      // alpha            [N,3]

    const int nt = (N + TILE - 1) / TILE;
    const int blocks = nt < GBLK ? nt : GBLK;
    alpha_kernel<<<blocks, BLOCK, 0, stream>>>(
        (const float4*)prnt, (const float4*)child, rel_mu, rel_sigma,
        (const float4*)eps, (const float4*)beta, (const float4*)rels,
        out0, out1, out2, out3, N, nmu);
}

// Round 6
// 337.538 us; speedup vs baseline: 1.0533x; 1.0109x over previous
//
#include <hip/hip_runtime.h>

#define BLOCK 256
#define ROWS  256                 // rows per block (1 per thread)
#define PCF4  (ROWS * 3 / 4)      // 192 float4 per block for prnt/child
#define EPSF4 (ROWS * 9 / 4)      // 576 float4 per block for eps

typedef const __attribute__((address_space(1))) void* gas1_t;
typedef __attribute__((address_space(3)))       void* las3_t;
typedef float __attribute__((ext_vector_type(4))) f32x4;   // native vec for nt-store

// Async direct-to-LDS 16B load: lane L of the wave loads g[L] (1KB/wave per
// issue) into LDS at (wave-uniform) l + L*16. Drained by __syncthreads().
__device__ __forceinline__ void ld_lds16(const float4* g, float4* l) {
    __builtin_amdgcn_global_load_lds((gas1_t)(const void*)g, (las3_t)(void*)l, 16, 0, 0);
}

// 16B nontemporal store (nt flag: no L2/L3 allocation).
__device__ __forceinline__ void nt_store16(const float4& v, float4* dst) {
    __builtin_nontemporal_store(*(const f32x4*)&v, (f32x4*)dst);
}

// 16.9 KB LDS, <=64 VGPR -> 8 blocks/CU (32 waves = full occupancy).
__global__ __launch_bounds__(BLOCK, 8) void alpha_kernel(
    const float4* __restrict__ prnt4,
    const float4* __restrict__ child4,
    const float*  __restrict__ rel_mu,
    const float*  __restrict__ rel_sigma,
    const float4* __restrict__ eps4,
    const float*  __restrict__ beta,
    const int*    __restrict__ rels,
    float*  __restrict__ out0,   // copy_mask        (N floats)
    float4* __restrict__ out1,   // child_probs2copy (3N floats)
    float*  __restrict__ out2,   // alpha_mask       (N floats)
    float4* __restrict__ out3,   // alpha            (3N floats)
    int n_rows, int nmu)
{
    __shared__ float4 s_p[PCF4];
    __shared__ float4 s_c[PCF4];
    __shared__ float4 s_e[EPSF4];
    __shared__ float  smu[192];
    __shared__ float  ssg[192];

    const int  tid       = threadIdx.x;
    const int  lane      = tid & 63;
    const int  wv        = tid >> 6;          // 4 waves per block
    const int  b         = blockIdx.x;
    const long rows_base = (long)b * ROWS;
    const int  rows_here = min(ROWS, (int)(n_rows - rows_base));
    const bool full      = (rows_here == ROWS);

    const float4* gp = prnt4  + (size_t)b * PCF4;
    const float4* gc = child4 + (size_t)b * PCF4;
    const float4* ge = eps4   + (size_t)b * EPSF4;

    // --- scalar loads issued first so their waitcnt doesn't drain the async queue
    float rmu = 0.0f, rsg = 0.0f;
    const bool has_mu = (tid < nmu);
    if (has_mu) { rmu = rel_mu[tid]; rsg = rel_sigma[tid]; }

    const bool active = (tid < rows_here);
    float bt = 0.0f;
    int   rq = 0;
    if (active) {
        bt = beta[rows_base + tid];
        rq = rels[rows_base + tid];
    }

    // --- async global->LDS staging, 64-float4 (1KB) chunks per wave issue
    if (full) {
        for (int c = wv; c < PCF4 / 64; c += 4) {          // 3 chunks total
            ld_lds16(gp + (c << 6) + lane, s_p + (c << 6));
            ld_lds16(gc + (c << 6) + lane, s_c + (c << 6));
        }
        for (int c = wv; c < EPSF4 / 64; c += 4) {         // 9 chunks total
            ld_lds16(ge + (c << 6) + lane, s_e + (c << 6));
        }
    } else {
        const int pcf4_here  = rows_here * 3 / 4;
        const int epsf4_here = rows_here * 9 / 4;
        const int pc_chunks  = pcf4_here >> 6;
        const int eps_chunks = epsf4_here >> 6;
        for (int c = wv; c < pc_chunks; c += 4) {
            ld_lds16(gp + (c << 6) + lane, s_p + (c << 6));
            ld_lds16(gc + (c << 6) + lane, s_c + (c << 6));
        }
        for (int c = wv; c < eps_chunks; c += 4) {
            ld_lds16(ge + (c << 6) + lane, s_e + (c << 6));
        }
        for (int i = (pc_chunks << 6) + tid; i < pcf4_here; i += BLOCK) {
            s_p[i] = gp[i];
            s_c[i] = gc[i];
        }
        for (int i = (eps_chunks << 6) + tid; i < epsf4_here; i += BLOCK) {
            s_e[i] = ge[i];
        }
    }

    if (has_mu) { smu[tid] = rmu; ssg[tid] = rsg; }
    __syncthreads();

    float o1[3], o3[3];
    float m0 = 0.0f, m2 = 0.0f;

    if (active) {
        const float* pf = (const float*)s_p;
        const float* cf = (const float*)s_c;
        const float* ef = (const float*)s_e;

        // strides 3 and 9 are coprime with 32 banks -> conflict-free
        float p[3], c[3], e[9];
        #pragma unroll
        for (int k = 0; k < 3; ++k) p[k] = pf[3 * tid + k];
        #pragma unroll
        for (int k = 0; k < 3; ++k) c[k] = cf[3 * tid + k];
        #pragma unroll
        for (int k = 0; k < 9; ++k) e[k] = ef[9 * tid + k];

        const float* mu = &smu[9 * rq];
        const float* sg = &ssg[9 * rq];

        // logits = (mu + sigma*eps) @ child
        float l[3];
        #pragma unroll
        for (int i = 0; i < 3; ++i) {
            float acc = 0.0f;
            #pragma unroll
            for (int j = 0; j < 3; ++j) {
                float m = fmaf(sg[3 * i + j], e[3 * i + j], mu[3 * i + j]);
                acc = fmaf(m, c[j], acc);
            }
            l[i] = acc;
        }
        // softmax (3-wide)
        float mx = fmaxf(l[0], fmaxf(l[1], l[2]));
        float e0 = __expf(l[0] - mx), e1 = __expf(l[1] - mx), e2 = __expf(l[2] - mx);
        float einv = 1.0f / (e0 + e1 + e2);
        float cp0 = e0 * einv, cp1 = e1 * einv, cp2 = e2 * einv;

        float csum = c[0] + c[1] + c[2];
        float psum = p[0] + p[1] + p[2];
        bool cmask = (csum != 0.0f);
        bool copy  = cmask && (psum == 0.0f);
        bool amask = cmask && (psum != 0.0f);

        // _scale(prnt, cp)
        float z0 = fmaxf(0.01f, p[0] + cp0);
        float z1 = fmaxf(0.01f, p[1] + cp1);
        float z2 = fmaxf(0.01f, p[2] + cp2);
        float zinv = 1.0f / (z0 + z1 + z2);
        z0 *= zinv; z1 *= zinv; z2 *= zinv;
        float ent = -(z0 * __logf(z0) + z1 * __logf(z1) + z2 * __logf(z2));
        float cosv = p[0] * cp0 + p[1] * cp1 + p[2] * cp2;
        float np2 = p[0] * p[0] + p[1] * p[1] + p[2] * p[2];
        float nc2 = cp0 * cp0 + cp1 * cp1 + cp2 * cp2;
        float npn = (np2 == 0.0f) ? 0.0f : sqrtf(np2);
        float ncn = (nc2 == 0.0f) ? 0.0f : sqrtf(nc2);
        float nrm = npn * ncn;
        nrm = (nrm == 0.0f) ? 1.0f : nrm;
        cosv = fmaxf(0.01f, cosv / nrm);
        float s = 42.0f * cosv / ent;

        float bb = bt, ob = 1.0f - bb;
        float a0 = fmaf(ob, p[0], bb * cp0) * s;
        float a1 = fmaf(ob, p[1], bb * cp1) * s;
        float a2 = fmaf(ob, p[2], bb * cp2) * s;

        m0 = copy  ? 1.0f : 0.0f;
        m2 = amask ? 1.0f : 0.0f;
        o1[0] = copy ? cp0 : 0.0f;
        o1[1] = copy ? cp1 : 0.0f;
        o1[2] = copy ? cp2 : 0.0f;
        o3[0] = amask ? a0 : 0.0f;
        o3[1] = amask ? a1 : 0.0f;
        o3[2] = amask ? a2 : 0.0f;
    }

    // All LDS input reads complete -> safe to reuse s_p/s_c for outputs.
    __syncthreads();

    if (active) {
        float* of1 = (float*)s_p;
        float* of3 = (float*)s_c;
        #pragma unroll
        for (int k = 0; k < 3; ++k) of1[3 * tid + k] = o1[k];
        #pragma unroll
        for (int k = 0; k < 3; ++k) of3[3 * tid + k] = o3[k];
        // nt: masks are write-once, never re-read -> don't allocate in L2/L3
        __builtin_nontemporal_store(m0, &out0[rows_base + tid]);
        __builtin_nontemporal_store(m2, &out2[rows_base + tid]);
    }
    __syncthreads();

    float4* g1 = out1 + (size_t)b * PCF4;
    float4* g3 = out3 + (size_t)b * PCF4;
    const int pcf4_here = rows_here * 3 / 4;
    for (int i = tid; i < pcf4_here; i += BLOCK) {
        // nt: streaming output, keep L3 for the 272 MB input working set
        nt_store16(s_p[i], &g1[i]);
        nt_store16(s_c[i], &g3[i]);
    }
}

extern "C" void kernel_launch(void* const* d_in, const int* in_sizes, int n_in,
                              void* d_out, int out_size, void* d_ws, size_t ws_size,
                              hipStream_t stream)
{
    const float* prnt      = (const float*)d_in[0];
    const float* child     = (const float*)d_in[1];
    const float* rel_mu    = (const float*)d_in[2];
    const float* rel_sigma = (const float*)d_in[3];
    const float* eps       = (const float*)d_in[4];
    const float* beta      = (const float*)d_in[5];
    const int*   rels      = (const int*)d_in[6];

    const int N   = in_sizes[5];   // 4,000,000
    const int nmu = in_sizes[2];   // 180

    float* out  = (float*)d_out;
    float* out0 = out;                      // copy_mask        [N]
    float* out1 = out + (size_t)N;          // child_probs2copy [N,3]
    float* out2 = out + (size_t)4 * N;      // alpha_mask       [N]
    float* out3 = out + (size_t)5 * N;      // alpha            [N,3]

    int blocks = (N + ROWS - 1) / ROWS;
    alpha_kernel<<<blocks, BLOCK, 0, stream>>>(
        (const float4*)prnt, (const float4*)child, rel_mu, rel_sigma,
        (const float4*)eps, beta, rels,
        out0, (float4*)out1, out2, (float4*)out3,
        N, nmu);
}

// Round 7
// 336.596 us; speedup vs baseline: 1.0563x; 1.0028x over previous
//
#include <hip/hip_runtime.h>

#define BLOCK 256
#define WPB   4                   // waves per block
#define TROWS 64                  // rows per wave-tile (1 row per lane)
#define TF4   272                 // float4 per tile buffer: 4352 B
// byte offsets inside a tile buffer
//   p [0,768) c [768,1536) e [1536,3840) beta [3840,4096) rels [4096,4352)

typedef const __attribute__((address_space(1))) void* gas1_t;
typedef __attribute__((address_space(3)))       void* las3_t;

// Async direct-to-LDS 16B load; counts in the ISSUING wave's vmcnt, and the
// LDS write is visible to that wave once vmcnt covers it -> no barrier needed
// when only the staging wave reads the data.
__device__ __forceinline__ void ld_lds16(const float4* g, float4* l) {
    __builtin_amdgcn_global_load_lds((gas1_t)(const void*)g, (las3_t)(void*)l, 16, 0, 0);
}

// counted per-wave wait; sched_barrier keeps hipcc from reordering around it
#define WAITV(N) do { asm volatile("s_waitcnt vmcnt(" #N ")" ::: "memory"); \
                      __builtin_amdgcn_sched_barrier(0); } while (0)

__device__ __forceinline__ void row_compute(
    const float* p, const float* c, const float* e,
    float bb, int rq, const float* smu, const float* ssg,
    float* o1, float* o3, float& m0v, float& m2v)
{
    const float* mu = &smu[9 * rq];
    const float* sg = &ssg[9 * rq];
    float l[3];
    #pragma unroll
    for (int i = 0; i < 3; ++i) {
        float acc = 0.0f;
        #pragma unroll
        for (int j = 0; j < 3; ++j) {
            float m = fmaf(sg[3 * i + j], e[3 * i + j], mu[3 * i + j]);
            acc = fmaf(m, c[j], acc);
        }
        l[i] = acc;
    }
    float mx = fmaxf(l[0], fmaxf(l[1], l[2]));
    float e0 = __expf(l[0] - mx), e1 = __expf(l[1] - mx), e2 = __expf(l[2] - mx);
    float einv = 1.0f / (e0 + e1 + e2);
    float cp0 = e0 * einv, cp1 = e1 * einv, cp2 = e2 * einv;

    float csum = c[0] + c[1] + c[2];
    float psum = p[0] + p[1] + p[2];
    bool cmask = (csum != 0.0f);
    bool copy  = cmask && (psum == 0.0f);
    bool amask = cmask && (psum != 0.0f);

    float z0 = fmaxf(0.01f, p[0] + cp0);
    float z1 = fmaxf(0.01f, p[1] + cp1);
    float z2 = fmaxf(0.01f, p[2] + cp2);
    float zinv = 1.0f / (z0 + z1 + z2);
    z0 *= zinv; z1 *= zinv; z2 *= zinv;
    float ent = -(z0 * __logf(z0) + z1 * __logf(z1) + z2 * __logf(z2));
    float cosv = p[0] * cp0 + p[1] * cp1 + p[2] * cp2;
    float np2 = p[0] * p[0] + p[1] * p[1] + p[2] * p[2];
    float nc2 = cp0 * cp0 + cp1 * cp1 + cp2 * cp2;
    float npn = (np2 == 0.0f) ? 0.0f : sqrtf(np2);
    float ncn = (nc2 == 0.0f) ? 0.0f : sqrtf(nc2);
    float nrm = npn * ncn;
    nrm = (nrm == 0.0f) ? 1.0f : nrm;
    cosv = fmaxf(0.01f, cosv / nrm);
    float s = 42.0f * cosv / ent;

    float ob = 1.0f - bb;
    float a0 = fmaf(ob, p[0], bb * cp0) * s;
    float a1 = fmaf(ob, p[1], bb * cp1) * s;
    float a2 = fmaf(ob, p[2], bb * cp2) * s;

    m0v = copy  ? 1.0f : 0.0f;
    m2v = amask ? 1.0f : 0.0f;
    o1[0] = copy ? cp0 : 0.0f;
    o1[1] = copy ? cp1 : 0.0f;
    o1[2] = copy ? cp2 : 0.0f;
    o3[0] = amask ? a0 : 0.0f;
    o3[1] = amask ? a1 : 0.0f;
    o3[2] = amask ? a2 : 0.0f;
}

// Per-wave double-buffered pipeline, ZERO barriers after the mu-table load.
// Each wave streams its own 64-row tiles via global_load_lds into a private
// LDS slice; counted vmcnt (never 0 in steady state) keeps one full tile +
// the previous stores in flight per wave at all times.
__global__ __launch_bounds__(BLOCK, 4) void alpha_kernel(
    const float4* __restrict__ prnt4,
    const float4* __restrict__ child4,
    const float*  __restrict__ rel_mu,
    const float*  __restrict__ rel_sigma,
    const float4* __restrict__ eps4,
    const float4* __restrict__ beta4,
    const float4* __restrict__ rels4,
    float*  __restrict__ out0,   // copy_mask        (N)
    float4* __restrict__ out1f4, // child_probs2copy (3N floats)
    float*  __restrict__ out2,   // alpha_mask       (N)
    float4* __restrict__ out3f4, // alpha            (3N floats)
    int n_rows, int nmu)
{
    __shared__ float4 s_tiles[WPB][2][TF4];   // 34.8 KB
    __shared__ float  smu[192], ssg[192];

    const int tid  = threadIdx.x;
    const int lane = tid & 63;
    const int wv   = tid >> 6;

    if (tid < nmu) { smu[tid] = rel_mu[tid]; ssg[tid] = rel_sigma[tid]; }
    __syncthreads();                          // the only barrier (drains mu loads)

    const long ntf   = n_rows / TROWS;        // full tiles
    const long wgid  = (long)blockIdx.x * WPB + wv;
    const long W     = (long)gridDim.x * WPB;
    const long nmine = (wgid < ntf) ? ((ntf - 1 - wgid) / W + 1) : 0;

    // stage 64-row tile t into this wave's buffer b (7 vmem ops, always)
    auto stage = [&](long t, int b) {
        float4* dst = &s_tiles[wv][b][0];
        const float4* gp = prnt4  + t * 48;
        const float4* gc = child4 + t * 48;
        const float4* ge = eps4   + t * 144;
        const float4* gb = beta4  + t * 16;
        const float4* gr = rels4  + t * 16;
        ld_lds16(ge + lane,      dst + 96);          // e chunk 0 (64 lanes)
        ld_lds16(ge + 64 + lane, dst + 160);         // e chunk 1 (64 lanes)
        if (lane < 48) {
            ld_lds16(gp + lane, dst + 0);            // p (768 B)
            ld_lds16(gc + lane, dst + 48);           // c (768 B)
        }
        if (lane < 16) {
            ld_lds16(ge + 128 + lane, dst + 224);    // e chunk 2 (256 B)
            ld_lds16(gb + lane,       dst + 240);    // beta (256 B)
            ld_lds16(gr + lane,       dst + 256);    // rels (256 B)
        }
    };

    if (nmine >= 1) stage(wgid, 0);
    if (nmine >= 2) stage(wgid + W, 1);

    long k = wgid;
    int  b = 0;
    for (long i = 0; i < nmine; ++i, k += W, b ^= 1) {
        const bool more = (i + 1 < nmine);    // stage(i+1) newer in queue (7)
        const bool prev = (i > 0);            // stores(i-1) newer in queue (4)
        if      (more && prev) { WAITV(11); }
        else if (more)         { WAITV(7);  }
        else if (prev)         { WAITV(4);  }
        else                   { WAITV(0);  }

        float* fw = (float*)&s_tiles[wv][b][0];
        const float* f = fw;
        float p[3], c[3], e[9];
        #pragma unroll
        for (int q = 0; q < 3; ++q) p[q] = f[3 * lane + q];          // stride 3: conflict-free
        #pragma unroll
        for (int q = 0; q < 3; ++q) c[q] = f[192 + 3 * lane + q];
        #pragma unroll
        for (int q = 0; q < 9; ++q) e[q] = f[384 + 9 * lane + q];    // stride 9: conflict-free
        const float bt = f[960 + lane];
        const int   rq = ((const int*)fw)[1024 + lane];

        float o1[3], o3[3], m0, m2;
        row_compute(p, c, e, bt, rq, smu, ssg, o1, o3, m0, m2);

        // bounce o1/o3 into the just-consumed p/c regions (wave-private)
        #pragma unroll
        for (int q = 0; q < 3; ++q) fw[3 * lane + q]       = o1[q];
        #pragma unroll
        for (int q = 0; q < 3; ++q) fw[192 + 3 * lane + q] = o3[q];

        // stores (4 vmem ops): masks coalesced dwords, o1/o3 coalesced 16B
        out0[k * 64 + lane] = m0;
        out2[k * 64 + lane] = m2;
        const float4* bf = (const float4*)fw;
        if (lane < 48) {
            out1f4[k * 48 + lane] = bf[lane];        // ds_read waits lgkm, then store
            out3f4[k * 48 + lane] = bf[48 + lane];
        }

        // prefetch tile i+2 into this buffer (LDS writes arrive long after the
        // bounce ds_reads above completed -> no WAR hazard)
        if (i + 2 < nmine) stage(k + 2 * W, b);
    }

    // ragged remainder rows (none at N=4M): direct global path, wave 0 only
    const long rem = ntf * TROWS;
    if (rem < n_rows && wgid == 0) {
        const long r = rem + lane;
        if (r < n_rows) {
            const float* gpf = (const float*)prnt4;
            const float* gcf = (const float*)child4;
            const float* gef = (const float*)eps4;
            float p[3], c[3], e[9];
            #pragma unroll
            for (int q = 0; q < 3; ++q) p[q] = gpf[3 * r + q];
            #pragma unroll
            for (int q = 0; q < 3; ++q) c[q] = gcf[3 * r + q];
            #pragma unroll
            for (int q = 0; q < 9; ++q) e[q] = gef[9 * r + q];
            const float bt = ((const float*)beta4)[r];
            const int   rq = ((const int*)rels4)[r];
            float o1[3], o3[3], m0, m2;
            row_compute(p, c, e, bt, rq, smu, ssg, o1, o3, m0, m2);
            out0[r] = m0;
            out2[r] = m2;
            float* o1f = (float*)out1f4;
            float* o3f = (float*)out3f4;
            #pragma unroll
            for (int q = 0; q < 3; ++q) o1f[3 * r + q] = o1[q];
            #pragma unroll
            for (int q = 0; q < 3; ++q) o3f[3 * r + q] = o3[q];
        }
    }
}

extern "C" void kernel_launch(void* const* d_in, const int* in_sizes, int n_in,
                              void* d_out, int out_size, void* d_ws, size_t ws_size,
                              hipStream_t stream)
{
    const float* prnt      = (const float*)d_in[0];
    const float* child     = (const float*)d_in[1];
    const float* rel_mu    = (const float*)d_in[2];
    const float* rel_sigma = (const float*)d_in[3];
    const float* eps       = (const float*)d_in[4];
    const float* beta      = (const float*)d_in[5];
    const int*   rels      = (const int*)d_in[6];

    const int N   = in_sizes[5];   // 4,000,000
    const int nmu = in_sizes[2];   // 180

    float* out  = (float*)d_out;
    float* out0 = out;                      // copy_mask        [N]
    float* out1 = out + (size_t)N;          // child_probs2copy [N,3]
    float* out2 = out + (size_t)4 * N;      // alpha_mask       [N]
    float* out3 = out + (size_t)5 * N;      // alpha            [N,3]

    // persistent-ish grid: 1024 blocks x 4 waves = 4096 wave-pipelines
    // (4 blocks/CU at 36.4 KB LDS each -> fully resident)
    int blocks = 1024;
    const long ntf = (long)N / TROWS;
    if (ntf < (long)blocks * WPB) blocks = (int)((ntf + WPB - 1) / WPB);
    if (blocks < 1) blocks = 1;

    alpha_kernel<<<blocks, BLOCK, 0, stream>>>(
        (const float4*)prnt, (const float4*)child, rel_mu, rel_sigma,
        (const float4*)eps, (const float4*)beta, (const float4*)rels,
        out0, (float4*)out1, out2, (float4*)out3,
        N, nmu);
}